// Round 2
// baseline (3462.083 us; speedup 1.0000x reference)
//
#include <hip/hip_runtime.h>
#include <hip/hip_bf16.h>

// Problem constants: N=100000 nodes, E=1200000 edges, D=64, K=3 hops.
#define GN 100000
#define GE 1200000
#define GD 64

// ---------------------------------------------------------------------------
// Runtime dtype detection (device-side, deterministic, runs every call).
// flags[0] = 1 if weight/alpha are bf16, 0 if fp32.
// flags[1] = 1 if edge_index is int64, 0 if int32.
// ---------------------------------------------------------------------------
__global__ void detect_kernel(const void* __restrict__ w,
                              const void* __restrict__ edge,
                              int* __restrict__ flags) {
    __shared__ int s_badw, s_edgenz;
    if (threadIdx.x == 0) { s_badw = 0; s_edgenz = 0; }
    __syncthreads();
    const unsigned short* wh = (const unsigned short*)w;
    const unsigned int*   ei = (const unsigned int*)edge;
    int badw = 0, edgenz = 0;
    for (int i = threadIdx.x; i < 4096; i += 256) {
        // interpret halfword i as bf16
        unsigned int bits = ((unsigned int)wh[i]) << 16;
        float v = __uint_as_float(bits);
        if (!(fabsf(v) <= 100.0f)) badw = 1;      // NaN/Inf/huge -> not bf16 data
        if ((i & 1) == 1 && ei[i] != 0u) edgenz = 1; // odd word nonzero -> not int64
    }
    if (badw)   atomicOr(&s_badw, 1);
    if (edgenz) atomicOr(&s_edgenz, 1);
    __syncthreads();
    if (threadIdx.x == 0) {
        flags[0] = s_badw   ? 0 : 1;   // bf16?
        flags[1] = s_edgenz ? 1 : 0;   // wait: edgenz==1 means int32
        flags[1] = s_edgenz ? 0 : 1;   // 1 = int64
    }
}

// ---- index loads (branch on int64 flag; little-endian low word) ----
__device__ __forceinline__ int ld_row(const int* __restrict__ edge, int e, int e64) {
    return e64 ? edge[2 * (size_t)e] : edge[e];
}
__device__ __forceinline__ int ld_col(const int* __restrict__ edge, int e, int e64) {
    return e64 ? edge[2 * ((size_t)GE + (size_t)e)] : edge[(size_t)GE + (size_t)e];
}
__device__ __forceinline__ float ld_f(const void* __restrict__ p, size_t i, int bf16f) {
    if (bf16f) return __bfloat162float(((const __hip_bfloat16*)p)[i]);
    return ((const float*)p)[i];
}

// ---- degree over col ----
__global__ void deg_kernel(const int* __restrict__ edge, const int* __restrict__ flags,
                           float* __restrict__ deg, int E) {
    int e = blockIdx.x * blockDim.x + threadIdx.x;
    int e64 = flags[1];
    if (e < E) {
        int c = ld_col(edge, e, e64);
        if ((unsigned)c < (unsigned)GN) atomicAdd(&deg[c], 1.0f);
    }
}

// ---- dinv = deg>0 ? deg^-1/2 : 0 (in place) ----
__global__ void dinv_kernel(float* __restrict__ deg, int n) {
    int i = blockIdx.x * blockDim.x + threadIdx.x;
    if (i < n) {
        float d = deg[i];
        deg[i] = (d > 0.0f) ? rsqrtf(d) : 0.0f;
    }
}

// ---- X = fp32(weight); OUT = alpha[0] * X ----
__global__ void init_kernel(const void* __restrict__ w, const void* __restrict__ alpha,
                            const int* __restrict__ flags,
                            float* __restrict__ X, float* __restrict__ OUT, int n) {
    int i = 4 * (blockIdx.x * blockDim.x + threadIdx.x);
    int wbf = flags[0];
    if (i < n) {
        float a0 = ld_f(alpha, 0, wbf);
        float4 v;
        v.x = ld_f(w, i + 0, wbf);
        v.y = ld_f(w, i + 1, wbf);
        v.z = ld_f(w, i + 2, wbf);
        v.w = ld_f(w, i + 3, wbf);
        *(float4*)(X + i) = v;
        float4 o;
        o.x = a0 * v.x; o.y = a0 * v.y; o.z = a0 * v.z; o.w = a0 * v.w;
        *(float4*)(OUT + i) = o;
    }
}

// ---- one hop: Y[col[e]] += dinv[row]*dinv[col] * X[row[e]]  (16 thr/edge, float4) ----
__global__ void scatter_kernel(const float* __restrict__ X, float* __restrict__ Y,
                               const int* __restrict__ edge, const int* __restrict__ flags,
                               const float* __restrict__ dinv, int E) {
    int t = blockIdx.x * blockDim.x + threadIdx.x;
    int e = t >> 4;
    int sub = t & 15;
    int e64 = flags[1];
    if (e < E) {
        int r = ld_row(edge, e, e64);
        int c = ld_col(edge, e, e64);
        if ((unsigned)r < (unsigned)GN && (unsigned)c < (unsigned)GN) {
            float w = dinv[r] * dinv[c];
            if (w != 0.0f) {
                float4 v = *(const float4*)(X + (size_t)r * GD + sub * 4);
                float* dst = Y + (size_t)c * GD + sub * 4;
                atomicAdd(dst + 0, w * v.x);
                atomicAdd(dst + 1, w * v.y);
                atomicAdd(dst + 2, w * v.z);
                atomicAdd(dst + 3, w * v.w);
            }
        }
    }
}

// ---- OUT += alpha[k] * X ----
__global__ void axpy_kernel(const float* __restrict__ X, const void* __restrict__ alpha,
                            const int* __restrict__ flags, int k,
                            float* __restrict__ OUT, int n) {
    int i = 4 * (blockIdx.x * blockDim.x + threadIdx.x);
    int wbf = flags[0];
    if (i < n) {
        float a = ld_f(alpha, k, wbf);
        float4 v = *(const float4*)(X + i);
        float4 o = *(const float4*)(OUT + i);
        o.x += a * v.x; o.y += a * v.y; o.z += a * v.z; o.w += a * v.w;
        *(float4*)(OUT + i) = o;
    }
}

// ---- res[e] = dot(OUT[row[e]], OUT[col[e]]) — one 64-lane wave per edge ----
__global__ void dot_kernel(const float* __restrict__ OUT,
                           const int* __restrict__ edge, const int* __restrict__ flags,
                           void* __restrict__ res, int E) {
    int t = blockIdx.x * blockDim.x + threadIdx.x;
    int e = t >> 6;
    int lane = t & 63;
    int e64 = flags[1];
    int wbf = flags[0];
    if (e < E) {
        int r = ld_row(edge, e, e64);
        int c = ld_col(edge, e, e64);
        float p = 0.0f;
        if ((unsigned)r < (unsigned)GN && (unsigned)c < (unsigned)GN) {
            p = OUT[(size_t)r * GD + lane] * OUT[(size_t)c * GD + lane];
        }
        #pragma unroll
        for (int off = 32; off > 0; off >>= 1) p += __shfl_down(p, off, 64);
        if (lane == 0) {
            if (wbf) ((__hip_bfloat16*)res)[e] = __float2bfloat16(p);
            else     ((float*)res)[e] = p;
        }
    }
}

extern "C" void kernel_launch(void* const* d_in, const int* in_sizes, int n_in,
                              void* d_out, int out_size, void* d_ws, size_t ws_size,
                              hipStream_t stream) {
    const int E = GE, N = GN, ND = GN * GD;

    const void* edge   = d_in[0];
    const void* weight = d_in[1];
    const void* alpha  = d_in[2];

    // Workspace layout: flags(256B) | deg/dinv (400128B) | X | Y | OUT (fp32 each)
    char* ws = (char*)d_ws;
    int*   flags = (int*)ws;   ws += 256;
    float* deg   = (float*)ws; ws += (((size_t)N * 4 + 255) / 256) * 256;
    float* X     = (float*)ws; ws += (size_t)ND * 4;
    float* Y     = (float*)ws; ws += (size_t)ND * 4;
    float* OUT   = (float*)ws; ws += (size_t)ND * 4;
    // total ~74 MiB

    const int B = 256;

    detect_kernel<<<1, 256, 0, stream>>>(weight, edge, flags);

    // normalization
    hipMemsetAsync(deg, 0, (size_t)N * 4, stream);
    deg_kernel<<<(E + B - 1) / B, B, 0, stream>>>((const int*)edge, flags, deg, E);
    dinv_kernel<<<(N + B - 1) / B, B, 0, stream>>>(deg, N);

    // X = fp32(weight); OUT = a0*X
    init_kernel<<<(ND / 4 + B - 1) / B, B, 0, stream>>>(weight, alpha, flags, X, OUT, ND);

    // hop 1: X -> Y
    hipMemsetAsync(Y, 0, (size_t)ND * 4, stream);
    scatter_kernel<<<((size_t)E * 16 + B - 1) / B, B, 0, stream>>>(X, Y, (const int*)edge, flags, deg, E);
    axpy_kernel<<<(ND / 4 + B - 1) / B, B, 0, stream>>>(Y, alpha, flags, 1, OUT, ND);

    // hop 2: Y -> X
    hipMemsetAsync(X, 0, (size_t)ND * 4, stream);
    scatter_kernel<<<((size_t)E * 16 + B - 1) / B, B, 0, stream>>>(Y, X, (const int*)edge, flags, deg, E);
    axpy_kernel<<<(ND / 4 + B - 1) / B, B, 0, stream>>>(X, alpha, flags, 2, OUT, ND);

    // hop 3: X -> Y
    hipMemsetAsync(Y, 0, (size_t)ND * 4, stream);
    scatter_kernel<<<((size_t)E * 16 + B - 1) / B, B, 0, stream>>>(X, Y, (const int*)edge, flags, deg, E);
    axpy_kernel<<<(ND / 4 + B - 1) / B, B, 0, stream>>>(Y, alpha, flags, 3, OUT, ND);

    // per-edge link scores
    dot_kernel<<<((size_t)E * 64 + B - 1) / B, B, 0, stream>>>(OUT, (const int*)edge, flags, d_out, E);
}

// Round 3
// 529.130 us; speedup vs baseline: 6.5430x; 6.5430x over previous
//
#include <hip/hip_runtime.h>
#include <hip/hip_bf16.h>

// Problem constants: N=100000 nodes, E=1200000 edges, D=64, K=3 hops.
#define GN 100000
#define GE 1200000
#define GD 64
#define SCAN_B 256

// ---------------------------------------------------------------------------
// Runtime dtype detection. flags[0]=1 if weight/alpha bf16 else fp32.
// flags[1]=1 if edge_index int64 else int32.
// ---------------------------------------------------------------------------
__global__ void detect_kernel(const void* __restrict__ w,
                              const void* __restrict__ edge,
                              int* __restrict__ flags) {
    __shared__ int s_badw, s_edgenz;
    if (threadIdx.x == 0) { s_badw = 0; s_edgenz = 0; }
    __syncthreads();
    const unsigned short* wh = (const unsigned short*)w;
    const unsigned int*   ei = (const unsigned int*)edge;
    int badw = 0, edgenz = 0;
    for (int i = threadIdx.x; i < 4096; i += 256) {
        unsigned int bits = ((unsigned int)wh[i]) << 16;
        float v = __uint_as_float(bits);
        if (!(fabsf(v) <= 100.0f)) badw = 1;         // NaN/Inf/huge -> fp32 backing
        if ((i & 1) == 1 && ei[i] != 0u) edgenz = 1; // odd word nonzero -> int32
    }
    if (badw)   atomicOr(&s_badw, 1);
    if (edgenz) atomicOr(&s_edgenz, 1);
    __syncthreads();
    if (threadIdx.x == 0) {
        flags[0] = s_badw ? 0 : 1;
        flags[1] = s_edgenz ? 0 : 1;
    }
}

__device__ __forceinline__ int ld_row(const int* __restrict__ edge, int e, int e64) {
    return e64 ? edge[2 * (size_t)e] : edge[e];
}
__device__ __forceinline__ int ld_col(const int* __restrict__ edge, int e, int e64) {
    return e64 ? edge[2 * ((size_t)GE + (size_t)e)] : edge[(size_t)GE + (size_t)e];
}
__device__ __forceinline__ float ld_f(const void* __restrict__ p, size_t i, int bf16f) {
    if (bf16f) return __bfloat162float(((const __hip_bfloat16*)p)[i]);
    return ((const float*)p)[i];
}

// ---- int histogram of col ----
__global__ void hist_kernel(const int* __restrict__ edge, const int* __restrict__ flags,
                            int* __restrict__ degi, int E) {
    int e = blockIdx.x * blockDim.x + threadIdx.x;
    int e64 = flags[1];
    if (e < E) {
        int c = ld_col(edge, e, e64);
        if ((unsigned)c < (unsigned)GN) atomicAdd(&degi[c], 1);
    }
}

// ---- dinv[i] = degi>0 ? degi^-1/2 : 0 ----
__global__ void dinv_kernel(const int* __restrict__ degi, float* __restrict__ dinv, int n) {
    int i = blockIdx.x * blockDim.x + threadIdx.x;
    if (i < n) {
        int d = degi[i];
        dinv[i] = (d > 0) ? rsqrtf((float)d) : 0.0f;
    }
}

// ---- 2-level exclusive scan: degi -> rowptr ----
__global__ void scan1_kernel(const int* __restrict__ degi, int* __restrict__ excl,
                             int* __restrict__ bsums, int n) {
    __shared__ int s[SCAN_B];
    int i = blockIdx.x * SCAN_B + threadIdx.x;
    int v = (i < n) ? degi[i] : 0;
    s[threadIdx.x] = v;
    __syncthreads();
    for (int off = 1; off < SCAN_B; off <<= 1) {
        int t = (threadIdx.x >= off) ? s[threadIdx.x - off] : 0;
        __syncthreads();
        s[threadIdx.x] += t;
        __syncthreads();
    }
    if (i < n) excl[i] = s[threadIdx.x] - v;
    if (threadIdx.x == SCAN_B - 1) bsums[blockIdx.x] = s[SCAN_B - 1];
}

__global__ void scan2_kernel(int* __restrict__ bsums, int nb) {
    __shared__ int s[512];
    int v = (threadIdx.x < nb) ? bsums[threadIdx.x] : 0;
    s[threadIdx.x] = v;
    __syncthreads();
    for (int off = 1; off < 512; off <<= 1) {
        int t = (threadIdx.x >= off) ? s[threadIdx.x - off] : 0;
        __syncthreads();
        s[threadIdx.x] += t;
        __syncthreads();
    }
    if (threadIdx.x < nb) bsums[threadIdx.x] = s[threadIdx.x] - v; // exclusive
}

__global__ void scan3_kernel(int* __restrict__ rowptr, const int* __restrict__ bsums, int n) {
    int i = blockIdx.x * SCAN_B + threadIdx.x;
    if (i < n) rowptr[i] += bsums[blockIdx.x];
}

// ---- CSR fill (shift trick: rowptr[c] post-fill == segment end) ----
__global__ void fill_kernel(const int* __restrict__ edge, const int* __restrict__ flags,
                            const float* __restrict__ dinv,
                            int* __restrict__ rowptr, int2* __restrict__ csr, int E) {
    int e = blockIdx.x * blockDim.x + threadIdx.x;
    int e64 = flags[1];
    if (e < E) {
        int r = ld_row(edge, e, e64);
        int c = ld_col(edge, e, e64);
        if ((unsigned)r < (unsigned)GN && (unsigned)c < (unsigned)GN) {
            float w = dinv[r] * dinv[c];
            int pos = atomicAdd(&rowptr[c], 1);
            csr[pos] = make_int2(r, __float_as_int(w));
        }
    }
}

// ---- X = fp32(weight); OUT = alpha[0] * X ----
__global__ void init_kernel(const void* __restrict__ w, const void* __restrict__ alpha,
                            const int* __restrict__ flags,
                            float* __restrict__ X, float* __restrict__ OUT, int n) {
    int i = 4 * (blockIdx.x * blockDim.x + threadIdx.x);
    int wbf = flags[0];
    if (i < n) {
        float a0 = ld_f(alpha, 0, wbf);
        float4 v;
        v.x = ld_f(w, i + 0, wbf);
        v.y = ld_f(w, i + 1, wbf);
        v.z = ld_f(w, i + 2, wbf);
        v.w = ld_f(w, i + 3, wbf);
        *(float4*)(X + i) = v;
        float4 o;
        o.x = a0 * v.x; o.y = a0 * v.y; o.z = a0 * v.z; o.w = a0 * v.w;
        *(float4*)(OUT + i) = o;
    }
}

// ---- one hop, gather form, fused axpy: one 64-lane wave per node ----
// Y[i,:] = sum_{e: col=i} w_e * X[row_e,:];  OUT[i,:] += alpha_k * Y[i,:]
__global__ void gather_kernel(const float* __restrict__ X, float* __restrict__ Y,
                              float* __restrict__ OUT,
                              const int* __restrict__ rowptr, const int2* __restrict__ csr,
                              const void* __restrict__ alpha, const int* __restrict__ flags,
                              int k, int N) {
    int t = blockIdx.x * blockDim.x + threadIdx.x;
    int node = __builtin_amdgcn_readfirstlane(t >> 6);
    int lane = t & 63;
    if (node < N) {
        int beg = node ? rowptr[node - 1] : 0;   // post-fill: rowptr[c] = end of segment c
        int end = rowptr[node];
        float acc = 0.0f;
        for (int j = beg; j < end; ++j) {
            int2 ent = csr[j];
            acc += __int_as_float(ent.y) * X[(size_t)ent.x * GD + lane];
        }
        size_t o = (size_t)node * GD + lane;
        Y[o] = acc;
        float a = ld_f(alpha, k, flags[0]);
        OUT[o] += a * acc;
    }
}

// ---- res[e] = dot(OUT[row[e]], OUT[col[e]]) — 16 threads/edge, float4 ----
__global__ void dot_kernel(const float* __restrict__ OUT,
                           const int* __restrict__ edge, const int* __restrict__ flags,
                           void* __restrict__ res, int E) {
    int t = blockIdx.x * blockDim.x + threadIdx.x;
    int e = t >> 4;
    int sub = t & 15;
    int e64 = flags[1];
    int wbf = flags[0];
    if (e < E) {
        int r = ld_row(edge, e, e64);
        int c = ld_col(edge, e, e64);
        float p = 0.0f;
        if ((unsigned)r < (unsigned)GN && (unsigned)c < (unsigned)GN) {
            float4 a = *(const float4*)(OUT + (size_t)r * GD + sub * 4);
            float4 b = *(const float4*)(OUT + (size_t)c * GD + sub * 4);
            p = a.x * b.x + a.y * b.y + a.z * b.z + a.w * b.w;
        }
        #pragma unroll
        for (int off = 8; off > 0; off >>= 1) p += __shfl_down(p, off, 16);
        if (sub == 0) {
            if (wbf) ((__hip_bfloat16*)res)[e] = __float2bfloat16(p);
            else     ((float*)res)[e] = p;
        }
    }
}

extern "C" void kernel_launch(void* const* d_in, const int* in_sizes, int n_in,
                              void* d_out, int out_size, void* d_ws, size_t ws_size,
                              hipStream_t stream) {
    const int E = GE, N = GN, ND = GN * GD;
    const int nblocks_scan = (N + SCAN_B - 1) / SCAN_B;  // 391

    const void* edge   = d_in[0];
    const void* weight = d_in[1];
    const void* alpha  = d_in[2];

    // Workspace layout
    char* ws = (char*)d_ws;
    int*   flags  = (int*)ws;   ws += 256;
    int*   degi   = (int*)ws;   ws += (((size_t)N * 4 + 255) / 256) * 256;
    float* dinv   = (float*)ws; ws += (((size_t)N * 4 + 255) / 256) * 256;
    int*   rowptr = (int*)ws;   ws += (((size_t)N * 4 + 255) / 256) * 256;
    int*   bsums  = (int*)ws;   ws += 2048;
    int2*  csr    = (int2*)ws;  ws += (size_t)E * 8;        // 9.6 MB
    float* X      = (float*)ws; ws += (size_t)ND * 4;       // 25.6 MB
    float* Y      = (float*)ws; ws += (size_t)ND * 4;       // 25.6 MB
    float* OUT    = (float*)ws; ws += (size_t)ND * 4;       // 25.6 MB
    // total ~88.4 MiB

    const int B = 256;

    detect_kernel<<<1, 256, 0, stream>>>(weight, edge, flags);

    // CSR build
    hipMemsetAsync(degi, 0, (size_t)N * 4, stream);
    hist_kernel<<<(E + B - 1) / B, B, 0, stream>>>((const int*)edge, flags, degi, E);
    dinv_kernel<<<(N + B - 1) / B, B, 0, stream>>>(degi, dinv, N);
    scan1_kernel<<<nblocks_scan, SCAN_B, 0, stream>>>(degi, rowptr, bsums, N);
    scan2_kernel<<<1, 512, 0, stream>>>(bsums, nblocks_scan);
    scan3_kernel<<<nblocks_scan, SCAN_B, 0, stream>>>(rowptr, bsums, N);
    fill_kernel<<<(E + B - 1) / B, B, 0, stream>>>((const int*)edge, flags, dinv, rowptr, csr, E);

    // X = fp32(weight); OUT = a0*X
    init_kernel<<<(ND / 4 + B - 1) / B, B, 0, stream>>>(weight, alpha, flags, X, OUT, ND);

    // 3 propagation hops (gather + fused axpy)
    const int gwaves = N;  // one wave per node
    const int ggrid = (int)(((size_t)gwaves * 64 + B - 1) / B);
    gather_kernel<<<ggrid, B, 0, stream>>>(X, Y, OUT, rowptr, csr, alpha, flags, 1, N);
    gather_kernel<<<ggrid, B, 0, stream>>>(Y, X, OUT, rowptr, csr, alpha, flags, 2, N);
    gather_kernel<<<ggrid, B, 0, stream>>>(X, Y, OUT, rowptr, csr, alpha, flags, 3, N);

    // per-edge link scores
    dot_kernel<<<(int)(((size_t)E * 16 + B - 1) / B), B, 0, stream>>>(OUT, (const int*)edge, flags, d_out, E);
}

// Round 5
// 446.670 us; speedup vs baseline: 7.7509x; 1.1846x over previous
//
#include <hip/hip_runtime.h>
#include <hip/hip_bf16.h>

// Problem constants: N=100000 nodes, E=1200000 edges, D=64, K=3 hops.
#define GN 100000
#define GE 1200000
#define GD 64
#define SCAN_B 256

// NOTE on workspace budget: round 3's layout (~87.6 MB) passed; round 4 added
// a 4.8 MB eid array (~92.4 MB) and corrupted memory past d_ws (launch 1 ok,
// all later launches wrong+slow => pristine-input corruption). Stay at the
// known-good footprint. Do NOT grow d_ws usage past round 3's layout.

// ---------------------------------------------------------------------------
// Runtime dtype detection. flags[0]=1 if weight/alpha bf16 else fp32.
// flags[1]=1 if edge_index int64 else int32.
// ---------------------------------------------------------------------------
__global__ void detect_kernel(const void* __restrict__ w,
                              const void* __restrict__ edge,
                              int* __restrict__ flags) {
    __shared__ int s_badw, s_edgenz;
    if (threadIdx.x == 0) { s_badw = 0; s_edgenz = 0; }
    __syncthreads();
    const unsigned short* wh = (const unsigned short*)w;
    const unsigned int*   ei = (const unsigned int*)edge;
    int badw = 0, edgenz = 0;
    for (int i = threadIdx.x; i < 4096; i += 256) {
        unsigned int bits = ((unsigned int)wh[i]) << 16;
        float v = __uint_as_float(bits);
        if (!(fabsf(v) <= 100.0f)) badw = 1;         // NaN/Inf/huge -> fp32 backing
        if ((i & 1) == 1 && ei[i] != 0u) edgenz = 1; // odd word nonzero -> int32
    }
    if (badw)   atomicOr(&s_badw, 1);
    if (edgenz) atomicOr(&s_edgenz, 1);
    __syncthreads();
    if (threadIdx.x == 0) {
        flags[0] = s_badw ? 0 : 1;
        flags[1] = s_edgenz ? 0 : 1;
    }
}

__device__ __forceinline__ int ld_row(const int* __restrict__ edge, int e, int e64) {
    return e64 ? edge[2 * (size_t)e] : edge[e];
}
__device__ __forceinline__ int ld_col(const int* __restrict__ edge, int e, int e64) {
    return e64 ? edge[2 * ((size_t)GE + (size_t)e)] : edge[(size_t)GE + (size_t)e];
}
__device__ __forceinline__ float ld_f(const void* __restrict__ p, size_t i, int bf16f) {
    if (bf16f) return __bfloat162float(((const __hip_bfloat16*)p)[i]);
    return ((const float*)p)[i];
}

// ---- int histogram of col ----
__global__ void hist_kernel(const int* __restrict__ edge, const int* __restrict__ flags,
                            int* __restrict__ degi, int E) {
    int e = blockIdx.x * blockDim.x + threadIdx.x;
    int e64 = flags[1];
    if (e < E) {
        int c = ld_col(edge, e, e64);
        if ((unsigned)c < (unsigned)GN) atomicAdd(&degi[c], 1);
    }
}

// ---- fused: block-level exclusive scan of degi + dinv computation ----
__global__ void scan1_kernel(const int* __restrict__ degi, int* __restrict__ excl,
                             int* __restrict__ bsums, float* __restrict__ dinv, int n) {
    __shared__ int s[SCAN_B];
    int i = blockIdx.x * SCAN_B + threadIdx.x;
    int v = (i < n) ? degi[i] : 0;
    if (i < n) dinv[i] = (v > 0) ? rsqrtf((float)v) : 0.0f;
    s[threadIdx.x] = v;
    __syncthreads();
    for (int off = 1; off < SCAN_B; off <<= 1) {
        int t = (threadIdx.x >= off) ? s[threadIdx.x - off] : 0;
        __syncthreads();
        s[threadIdx.x] += t;
        __syncthreads();
    }
    if (i < n) excl[i] = s[threadIdx.x] - v;
    if (threadIdx.x == SCAN_B - 1) bsums[blockIdx.x] = s[SCAN_B - 1];
}

__global__ void scan2_kernel(int* __restrict__ bsums, int nb) {
    __shared__ int s[512];
    int v = (threadIdx.x < nb) ? bsums[threadIdx.x] : 0;
    s[threadIdx.x] = v;
    __syncthreads();
    for (int off = 1; off < 512; off <<= 1) {
        int t = (threadIdx.x >= off) ? s[threadIdx.x - off] : 0;
        __syncthreads();
        s[threadIdx.x] += t;
        __syncthreads();
    }
    if (threadIdx.x < nb) bsums[threadIdx.x] = s[threadIdx.x] - v; // exclusive
}

__global__ void scan3_kernel(int* __restrict__ rowptr, const int* __restrict__ bsums, int n) {
    int i = blockIdx.x * SCAN_B + threadIdx.x;
    if (i < n) rowptr[i] += bsums[blockIdx.x];
}

// ---- CSR fill (shift trick: rowptr[c] post-fill == segment end) ----
__global__ void fill_kernel(const int* __restrict__ edge, const int* __restrict__ flags,
                            const float* __restrict__ dinv,
                            int* __restrict__ rowptr, int2* __restrict__ csr, int E) {
    int e = blockIdx.x * blockDim.x + threadIdx.x;
    int e64 = flags[1];
    if (e < E) {
        int r = ld_row(edge, e, e64);
        int c = ld_col(edge, e, e64);
        if ((unsigned)r < (unsigned)GN && (unsigned)c < (unsigned)GN) {
            float w = dinv[r] * dinv[c];
            int pos = atomicAdd(&rowptr[c], 1);
            csr[pos] = make_int2(r, __float_as_int(w));
        }
    }
}

// ---- X = fp32(weight); OUT = alpha[0] * X ----
__global__ void init_kernel(const void* __restrict__ w, const void* __restrict__ alpha,
                            const int* __restrict__ flags,
                            float* __restrict__ X, float* __restrict__ OUT, int n) {
    int i = 4 * (blockIdx.x * blockDim.x + threadIdx.x);
    int wbf = flags[0];
    if (i < n) {
        float a0 = ld_f(alpha, 0, wbf);
        float4 v;
        v.x = ld_f(w, i + 0, wbf);
        v.y = ld_f(w, i + 1, wbf);
        v.z = ld_f(w, i + 2, wbf);
        v.w = ld_f(w, i + 3, wbf);
        *(float4*)(X + i) = v;
        float4 o;
        o.x = a0 * v.x; o.y = a0 * v.y; o.z = a0 * v.z; o.w = a0 * v.w;
        *(float4*)(OUT + i) = o;
    }
}

// ---- one hop, gather form, fused axpy, 4-way unrolled for MLP ----
// Y[i,:] = sum_{e: col=i} w_e * X[row_e,:];  OUT[i,:] += alpha_k * Y[i,:]
__global__ void gather_kernel(const float* __restrict__ X, float* __restrict__ Y,
                              float* __restrict__ OUT,
                              const int* __restrict__ rowptr, const int2* __restrict__ csr,
                              const void* __restrict__ alpha, const int* __restrict__ flags,
                              int k, int N) {
    int t = blockIdx.x * blockDim.x + threadIdx.x;
    int node = __builtin_amdgcn_readfirstlane(t >> 6);
    int lane = t & 63;
    if (node >= N) return;
    float a = ld_f(alpha, k, flags[0]);
    int beg = node ? rowptr[node - 1] : 0;   // post-fill: rowptr[c] = end of segment c
    int end = rowptr[node];
    float a0 = 0.0f, a1 = 0.0f, a2 = 0.0f, a3 = 0.0f;
    int j = beg;
    for (; j + 4 <= end; j += 4) {
        int2 e0 = csr[j + 0];
        int2 e1 = csr[j + 1];
        int2 e2 = csr[j + 2];
        int2 e3 = csr[j + 3];
        float x0 = X[(size_t)e0.x * GD + lane];
        float x1 = X[(size_t)e1.x * GD + lane];
        float x2 = X[(size_t)e2.x * GD + lane];
        float x3 = X[(size_t)e3.x * GD + lane];
        a0 = fmaf(__int_as_float(e0.y), x0, a0);
        a1 = fmaf(__int_as_float(e1.y), x1, a1);
        a2 = fmaf(__int_as_float(e2.y), x2, a2);
        a3 = fmaf(__int_as_float(e3.y), x3, a3);
    }
    for (; j < end; ++j) {
        int2 e = csr[j];
        a0 = fmaf(__int_as_float(e.y), X[(size_t)e.x * GD + lane], a0);
    }
    float acc = (a0 + a1) + (a2 + a3);
    size_t o = (size_t)node * GD + lane;
    Y[o] = acc;
    OUT[o] += a * acc;
}

// ---- res[e] = dot(OUT[row[e]], OUT[col[e]]) — 16 threads/edge, float4 ----
__global__ void dot_kernel(const float* __restrict__ OUT,
                           const int* __restrict__ edge, const int* __restrict__ flags,
                           void* __restrict__ res, int E) {
    int t = blockIdx.x * blockDim.x + threadIdx.x;
    int e = t >> 4;
    int sub = t & 15;
    int e64 = flags[1];
    int wbf = flags[0];
    if (e < E) {
        int r = ld_row(edge, e, e64);
        int c = ld_col(edge, e, e64);
        float p = 0.0f;
        if ((unsigned)r < (unsigned)GN && (unsigned)c < (unsigned)GN) {
            float4 a = *(const float4*)(OUT + (size_t)r * GD + sub * 4);
            float4 b = *(const float4*)(OUT + (size_t)c * GD + sub * 4);
            p = a.x * b.x + a.y * b.y + a.z * b.z + a.w * b.w;
        }
        #pragma unroll
        for (int off = 8; off > 0; off >>= 1) p += __shfl_down(p, off, 16);
        if (sub == 0) {
            if (wbf) ((__hip_bfloat16*)res)[e] = __float2bfloat16(p);
            else     ((float*)res)[e] = p;
        }
    }
}

extern "C" void kernel_launch(void* const* d_in, const int* in_sizes, int n_in,
                              void* d_out, int out_size, void* d_ws, size_t ws_size,
                              hipStream_t stream) {
    const int E = GE, N = GN, ND = GN * GD;
    const int nblocks_scan = (N + SCAN_B - 1) / SCAN_B;  // 391

    const void* edge   = d_in[0];
    const void* weight = d_in[1];
    const void* alpha  = d_in[2];

    // Workspace layout — identical footprint to round 3 (known good, ~87.6 MB)
    char* ws = (char*)d_ws;
    int*   flags  = (int*)ws;   ws += 256;
    int*   degi   = (int*)ws;   ws += (((size_t)N * 4 + 255) / 256) * 256;
    float* dinv   = (float*)ws; ws += (((size_t)N * 4 + 255) / 256) * 256;
    int*   rowptr = (int*)ws;   ws += (((size_t)N * 4 + 255) / 256) * 256;
    int*   bsums  = (int*)ws;   ws += 2048;
    int2*  csr    = (int2*)ws;  ws += (size_t)E * 8;        // 9.6 MB
    float* X      = (float*)ws; ws += (size_t)ND * 4;       // 25.6 MB
    float* Y      = (float*)ws; ws += (size_t)ND * 4;       // 25.6 MB
    float* OUT    = (float*)ws; ws += (size_t)ND * 4;       // 25.6 MB

    const int B = 256;

    detect_kernel<<<1, 256, 0, stream>>>(weight, edge, flags);

    // CSR build
    hipMemsetAsync(degi, 0, (size_t)N * 4, stream);
    hist_kernel<<<(E + B - 1) / B, B, 0, stream>>>((const int*)edge, flags, degi, E);
    scan1_kernel<<<nblocks_scan, SCAN_B, 0, stream>>>(degi, rowptr, bsums, dinv, N);
    scan2_kernel<<<1, 512, 0, stream>>>(bsums, nblocks_scan);
    scan3_kernel<<<nblocks_scan, SCAN_B, 0, stream>>>(rowptr, bsums, N);
    fill_kernel<<<(E + B - 1) / B, B, 0, stream>>>((const int*)edge, flags, dinv, rowptr, csr, E);

    // X = fp32(weight); OUT = a0*X
    init_kernel<<<(ND / 4 + B - 1) / B, B, 0, stream>>>(weight, alpha, flags, X, OUT, ND);

    // 3 propagation hops (gather + fused axpy, 4-way unrolled)
    const int ggrid = (int)(((size_t)N * 64 + B - 1) / B);
    gather_kernel<<<ggrid, B, 0, stream>>>(X, Y, OUT, rowptr, csr, alpha, flags, 1, N);
    gather_kernel<<<ggrid, B, 0, stream>>>(Y, X, OUT, rowptr, csr, alpha, flags, 2, N);
    gather_kernel<<<ggrid, B, 0, stream>>>(X, Y, OUT, rowptr, csr, alpha, flags, 3, N);

    // per-edge link scores
    dot_kernel<<<(int)(((size_t)E * 16 + B - 1) / B), B, 0, stream>>>(OUT, (const int*)edge, flags, d_out, E);
}

// Round 6
// 397.915 us; speedup vs baseline: 8.7005x; 1.1225x over previous
//
#include <hip/hip_runtime.h>
#include <hip/hip_bf16.h>

// Problem constants: N=100000 nodes, E=1200000 edges, D=64, K=3 hops.
#define GN 100000
#define GE 1200000
#define GD 64
#define SCAN_B 256

// WS budget note: round-4 showed ws_size < ~92 MB (overflow corrupted pristine
// inputs). This layout uses ~50 MB (X/Y/OUT in bf16). Keep it well under 87.6.

// ---------------------------------------------------------------------------
// Runtime dtype detection. flags[0]=1 if weight/alpha bf16 else fp32.
// flags[1]=1 if edge_index int64 else int32.
// ---------------------------------------------------------------------------
__global__ void detect_kernel(const void* __restrict__ w,
                              const void* __restrict__ edge,
                              int* __restrict__ flags) {
    __shared__ int s_badw, s_edgenz;
    if (threadIdx.x == 0) { s_badw = 0; s_edgenz = 0; }
    __syncthreads();
    const unsigned short* wh = (const unsigned short*)w;
    const unsigned int*   ei = (const unsigned int*)edge;
    int badw = 0, edgenz = 0;
    for (int i = threadIdx.x; i < 4096; i += 256) {
        unsigned int bits = ((unsigned int)wh[i]) << 16;
        float v = __uint_as_float(bits);
        if (!(fabsf(v) <= 100.0f)) badw = 1;         // NaN/Inf/huge -> fp32 backing
        if ((i & 1) == 1 && ei[i] != 0u) edgenz = 1; // odd word nonzero -> int32
    }
    if (badw)   atomicOr(&s_badw, 1);
    if (edgenz) atomicOr(&s_edgenz, 1);
    __syncthreads();
    if (threadIdx.x == 0) {
        flags[0] = s_badw ? 0 : 1;
        flags[1] = s_edgenz ? 0 : 1;
    }
}

__device__ __forceinline__ int ld_row(const int* __restrict__ edge, int e, int e64) {
    return e64 ? edge[2 * (size_t)e] : edge[e];
}
__device__ __forceinline__ int ld_col(const int* __restrict__ edge, int e, int e64) {
    return e64 ? edge[2 * ((size_t)GE + (size_t)e)] : edge[(size_t)GE + (size_t)e];
}
__device__ __forceinline__ float ld_f(const void* __restrict__ p, size_t i, int bf16f) {
    if (bf16f) return __bfloat162float(((const __hip_bfloat16*)p)[i]);
    return ((const float*)p)[i];
}

// ---- int histogram of col ----
__global__ void hist_kernel(const int* __restrict__ edge, const int* __restrict__ flags,
                            int* __restrict__ degi, int E) {
    int e = blockIdx.x * blockDim.x + threadIdx.x;
    int e64 = flags[1];
    if (e < E) {
        int c = ld_col(edge, e, e64);
        if ((unsigned)c < (unsigned)GN) atomicAdd(&degi[c], 1);
    }
}

// ---- fused: block-level exclusive scan of degi + dinv computation ----
__global__ void scan1_kernel(const int* __restrict__ degi, int* __restrict__ excl,
                             int* __restrict__ bsums, float* __restrict__ dinv, int n) {
    __shared__ int s[SCAN_B];
    int i = blockIdx.x * SCAN_B + threadIdx.x;
    int v = (i < n) ? degi[i] : 0;
    if (i < n) dinv[i] = (v > 0) ? rsqrtf((float)v) : 0.0f;
    s[threadIdx.x] = v;
    __syncthreads();
    for (int off = 1; off < SCAN_B; off <<= 1) {
        int t = (threadIdx.x >= off) ? s[threadIdx.x - off] : 0;
        __syncthreads();
        s[threadIdx.x] += t;
        __syncthreads();
    }
    if (i < n) excl[i] = s[threadIdx.x] - v;
    if (threadIdx.x == SCAN_B - 1) bsums[blockIdx.x] = s[SCAN_B - 1];
}

__global__ void scan2_kernel(int* __restrict__ bsums, int nb) {
    __shared__ int s[512];
    int v = (threadIdx.x < nb) ? bsums[threadIdx.x] : 0;
    s[threadIdx.x] = v;
    __syncthreads();
    for (int off = 1; off < 512; off <<= 1) {
        int t = (threadIdx.x >= off) ? s[threadIdx.x - off] : 0;
        __syncthreads();
        s[threadIdx.x] += t;
        __syncthreads();
    }
    if (threadIdx.x < nb) bsums[threadIdx.x] = s[threadIdx.x] - v; // exclusive
}

__global__ void scan3_kernel(int* __restrict__ rowptr, const int* __restrict__ bsums, int n) {
    int i = blockIdx.x * SCAN_B + threadIdx.x;
    if (i < n) rowptr[i] += bsums[blockIdx.x];
}

// ---- CSR fill (shift trick: rowptr[c] post-fill == segment end) ----
__global__ void fill_kernel(const int* __restrict__ edge, const int* __restrict__ flags,
                            const float* __restrict__ dinv,
                            int* __restrict__ rowptr, int2* __restrict__ csr, int E) {
    int e = blockIdx.x * blockDim.x + threadIdx.x;
    int e64 = flags[1];
    if (e < E) {
        int r = ld_row(edge, e, e64);
        int c = ld_col(edge, e, e64);
        if ((unsigned)r < (unsigned)GN && (unsigned)c < (unsigned)GN) {
            float w = dinv[r] * dinv[c];
            int pos = atomicAdd(&rowptr[c], 1);
            csr[pos] = make_int2(r, __float_as_int(w));
        }
    }
}

// ---- X = bf16(weight); OUT = bf16(alpha[0] * weight) ----
__global__ void init_kernel(const void* __restrict__ w, const void* __restrict__ alpha,
                            const int* __restrict__ flags,
                            __hip_bfloat16* __restrict__ X, __hip_bfloat16* __restrict__ OUT,
                            int n) {
    int i = 4 * (blockIdx.x * blockDim.x + threadIdx.x);
    int wbf = flags[0];
    if (i < n) {
        float a0 = ld_f(alpha, 0, wbf);
        #pragma unroll
        for (int q = 0; q < 4; ++q) {
            float v = ld_f(w, i + q, wbf);
            X[i + q] = __float2bfloat16(v);        // hop-1 operand: exact bf16 input
            OUT[i + q] = __float2bfloat16(a0 * v);
        }
    }
}

// ---- one hop, gather form, fused axpy, 4-way unrolled; bf16 rows ----
// Y[i,:] = bf16( sum_{e: col=i} w_e * X[row_e,:] );  OUT[i,:] += alpha_k * acc
__global__ void gather_kernel(const __hip_bfloat16* __restrict__ X,
                              __hip_bfloat16* __restrict__ Y,
                              __hip_bfloat16* __restrict__ OUT,
                              const int* __restrict__ rowptr, const int2* __restrict__ csr,
                              const void* __restrict__ alpha, const int* __restrict__ flags,
                              int k, int N) {
    int t = blockIdx.x * blockDim.x + threadIdx.x;
    int node = __builtin_amdgcn_readfirstlane(t >> 6);
    int lane = t & 63;
    if (node >= N) return;
    float a = ld_f(alpha, k, flags[0]);
    int beg = node ? rowptr[node - 1] : 0;   // post-fill: rowptr[c] = end of segment c
    int end = rowptr[node];
    float a0 = 0.0f, a1 = 0.0f, a2 = 0.0f, a3 = 0.0f;
    int j = beg;
    for (; j + 4 <= end; j += 4) {
        int2 e0 = csr[j + 0];
        int2 e1 = csr[j + 1];
        int2 e2 = csr[j + 2];
        int2 e3 = csr[j + 3];
        float x0 = __bfloat162float(X[(size_t)e0.x * GD + lane]);
        float x1 = __bfloat162float(X[(size_t)e1.x * GD + lane]);
        float x2 = __bfloat162float(X[(size_t)e2.x * GD + lane]);
        float x3 = __bfloat162float(X[(size_t)e3.x * GD + lane]);
        a0 = fmaf(__int_as_float(e0.y), x0, a0);
        a1 = fmaf(__int_as_float(e1.y), x1, a1);
        a2 = fmaf(__int_as_float(e2.y), x2, a2);
        a3 = fmaf(__int_as_float(e3.y), x3, a3);
    }
    for (; j < end; ++j) {
        int2 e = csr[j];
        a0 = fmaf(__int_as_float(e.y), __bfloat162float(X[(size_t)e.x * GD + lane]), a0);
    }
    float acc = (a0 + a1) + (a2 + a3);
    size_t o = (size_t)node * GD + lane;
    Y[o] = __float2bfloat16(acc);
    OUT[o] = __float2bfloat16(__bfloat162float(OUT[o]) + a * acc);
}

// ---- res[e] = dot(OUT[row[e]], OUT[col[e]]) — 16 threads/edge, 4 bf16 each ----
__global__ void dot_kernel(const __hip_bfloat16* __restrict__ OUT,
                           const int* __restrict__ edge, const int* __restrict__ flags,
                           void* __restrict__ res, int E) {
    int t = blockIdx.x * blockDim.x + threadIdx.x;
    int e = t >> 4;
    int sub = t & 15;
    int e64 = flags[1];
    int wbf = flags[0];
    if (e < E) {
        int r = ld_row(edge, e, e64);
        int c = ld_col(edge, e, e64);
        float p = 0.0f;
        if ((unsigned)r < (unsigned)GN && (unsigned)c < (unsigned)GN) {
            ushort4 ua = *(const ushort4*)(OUT + (size_t)r * GD + sub * 4);
            ushort4 ub = *(const ushort4*)(OUT + (size_t)c * GD + sub * 4);
            float ax = __uint_as_float(((unsigned)ua.x) << 16);
            float ay = __uint_as_float(((unsigned)ua.y) << 16);
            float az = __uint_as_float(((unsigned)ua.z) << 16);
            float aw = __uint_as_float(((unsigned)ua.w) << 16);
            float bx = __uint_as_float(((unsigned)ub.x) << 16);
            float by = __uint_as_float(((unsigned)ub.y) << 16);
            float bz = __uint_as_float(((unsigned)ub.z) << 16);
            float bw = __uint_as_float(((unsigned)ub.w) << 16);
            p = ax * bx + ay * by + az * bz + aw * bw;
        }
        #pragma unroll
        for (int off = 8; off > 0; off >>= 1) p += __shfl_down(p, off, 16);
        if (sub == 0) {
            if (wbf) ((__hip_bfloat16*)res)[e] = __float2bfloat16(p);
            else     ((float*)res)[e] = p;
        }
    }
}

extern "C" void kernel_launch(void* const* d_in, const int* in_sizes, int n_in,
                              void* d_out, int out_size, void* d_ws, size_t ws_size,
                              hipStream_t stream) {
    const int E = GE, N = GN, ND = GN * GD;
    const int nblocks_scan = (N + SCAN_B - 1) / SCAN_B;  // 391

    const void* edge   = d_in[0];
    const void* weight = d_in[1];
    const void* alpha  = d_in[2];

    // Workspace layout (~50 MB total, bf16 feature buffers)
    char* ws = (char*)d_ws;
    int*   flags  = (int*)ws;   ws += 256;
    int*   degi   = (int*)ws;   ws += (((size_t)N * 4 + 255) / 256) * 256;
    float* dinv   = (float*)ws; ws += (((size_t)N * 4 + 255) / 256) * 256;
    int*   rowptr = (int*)ws;   ws += (((size_t)N * 4 + 255) / 256) * 256;
    int*   bsums  = (int*)ws;   ws += 2048;
    int2*  csr    = (int2*)ws;  ws += (size_t)E * 8;              // 9.6 MB
    __hip_bfloat16* X   = (__hip_bfloat16*)ws; ws += (size_t)ND * 2;  // 12.8 MB
    __hip_bfloat16* Y   = (__hip_bfloat16*)ws; ws += (size_t)ND * 2;  // 12.8 MB
    __hip_bfloat16* OUT = (__hip_bfloat16*)ws; ws += (size_t)ND * 2;  // 12.8 MB

    const int B = 256;

    detect_kernel<<<1, 256, 0, stream>>>(weight, edge, flags);

    // CSR build
    hipMemsetAsync(degi, 0, (size_t)N * 4, stream);
    hist_kernel<<<(E + B - 1) / B, B, 0, stream>>>((const int*)edge, flags, degi, E);
    scan1_kernel<<<nblocks_scan, SCAN_B, 0, stream>>>(degi, rowptr, bsums, dinv, N);
    scan2_kernel<<<1, 512, 0, stream>>>(bsums, nblocks_scan);
    scan3_kernel<<<nblocks_scan, SCAN_B, 0, stream>>>(rowptr, bsums, N);
    fill_kernel<<<(E + B - 1) / B, B, 0, stream>>>((const int*)edge, flags, dinv, rowptr, csr, E);

    // X = bf16(weight); OUT = bf16(a0*weight)
    init_kernel<<<(ND / 4 + B - 1) / B, B, 0, stream>>>(weight, alpha, flags, X, OUT, ND);

    // 3 propagation hops (gather + fused axpy, 4-way unrolled, bf16 rows)
    const int ggrid = (int)(((size_t)N * 64 + B - 1) / B);
    gather_kernel<<<ggrid, B, 0, stream>>>(X, Y, OUT, rowptr, csr, alpha, flags, 1, N);
    gather_kernel<<<ggrid, B, 0, stream>>>(Y, X, OUT, rowptr, csr, alpha, flags, 2, N);
    gather_kernel<<<ggrid, B, 0, stream>>>(X, Y, OUT, rowptr, csr, alpha, flags, 3, N);

    // per-edge link scores
    dot_kernel<<<(int)(((size_t)E * 16 + B - 1) / B), B, 0, stream>>>(OUT, (const int*)edge, flags, d_out, E);
}

// Round 7
// 361.615 us; speedup vs baseline: 9.5740x; 1.1004x over previous
//
#include <hip/hip_runtime.h>
#include <hip/hip_bf16.h>

// Problem constants: N=100000 nodes, E=1200000 edges, D=64, K=3 hops.
#define GN 100000
#define GE 1200000
#define GD 64
#define SCAN_B 256

// WS budget note: round-4 showed ws_size < ~92 MB (overflow corrupted pristine
// inputs). This layout uses ~50 MB (X/Y/OUT in bf16). Keep it well under 87.6.

// ---------------------------------------------------------------------------
// Runtime dtype detection. flags[0]=1 if weight/alpha bf16 else fp32.
// flags[1]=1 if edge_index int64 else int32.
// ---------------------------------------------------------------------------
__global__ void detect_kernel(const void* __restrict__ w,
                              const void* __restrict__ edge,
                              int* __restrict__ flags) {
    __shared__ int s_badw, s_edgenz;
    if (threadIdx.x == 0) { s_badw = 0; s_edgenz = 0; }
    __syncthreads();
    const unsigned short* wh = (const unsigned short*)w;
    const unsigned int*   ei = (const unsigned int*)edge;
    int badw = 0, edgenz = 0;
    for (int i = threadIdx.x; i < 4096; i += 256) {
        unsigned int bits = ((unsigned int)wh[i]) << 16;
        float v = __uint_as_float(bits);
        if (!(fabsf(v) <= 100.0f)) badw = 1;         // NaN/Inf/huge -> fp32 backing
        if ((i & 1) == 1 && ei[i] != 0u) edgenz = 1; // odd word nonzero -> int32
    }
    if (badw)   atomicOr(&s_badw, 1);
    if (edgenz) atomicOr(&s_edgenz, 1);
    __syncthreads();
    if (threadIdx.x == 0) {
        flags[0] = s_badw ? 0 : 1;
        flags[1] = s_edgenz ? 0 : 1;
    }
}

__device__ __forceinline__ int ld_row(const int* __restrict__ edge, int e, int e64) {
    return e64 ? edge[2 * (size_t)e] : edge[e];
}
__device__ __forceinline__ int ld_col(const int* __restrict__ edge, int e, int e64) {
    return e64 ? edge[2 * ((size_t)GE + (size_t)e)] : edge[(size_t)GE + (size_t)e];
}
__device__ __forceinline__ float ld_f(const void* __restrict__ p, size_t i, int bf16f) {
    if (bf16f) return __bfloat162float(((const __hip_bfloat16*)p)[i]);
    return ((const float*)p)[i];
}

// ---- int histogram of col ----
__global__ void hist_kernel(const int* __restrict__ edge, const int* __restrict__ flags,
                            int* __restrict__ degi, int E) {
    int e = blockIdx.x * blockDim.x + threadIdx.x;
    int e64 = flags[1];
    if (e < E) {
        int c = ld_col(edge, e, e64);
        if ((unsigned)c < (unsigned)GN) atomicAdd(&degi[c], 1);
    }
}

// ---- fused: block-level exclusive scan of degi + dinv computation ----
__global__ void scan1_kernel(const int* __restrict__ degi, int* __restrict__ excl,
                             int* __restrict__ bsums, float* __restrict__ dinv, int n) {
    __shared__ int s[SCAN_B];
    int i = blockIdx.x * SCAN_B + threadIdx.x;
    int v = (i < n) ? degi[i] : 0;
    if (i < n) dinv[i] = (v > 0) ? rsqrtf((float)v) : 0.0f;
    s[threadIdx.x] = v;
    __syncthreads();
    for (int off = 1; off < SCAN_B; off <<= 1) {
        int t = (threadIdx.x >= off) ? s[threadIdx.x - off] : 0;
        __syncthreads();
        s[threadIdx.x] += t;
        __syncthreads();
    }
    if (i < n) excl[i] = s[threadIdx.x] - v;
    if (threadIdx.x == SCAN_B - 1) bsums[blockIdx.x] = s[SCAN_B - 1];
}

__global__ void scan2_kernel(int* __restrict__ bsums, int nb) {
    __shared__ int s[512];
    int v = (threadIdx.x < nb) ? bsums[threadIdx.x] : 0;
    s[threadIdx.x] = v;
    __syncthreads();
    for (int off = 1; off < 512; off <<= 1) {
        int t = (threadIdx.x >= off) ? s[threadIdx.x - off] : 0;
        __syncthreads();
        s[threadIdx.x] += t;
        __syncthreads();
    }
    if (threadIdx.x < nb) bsums[threadIdx.x] = s[threadIdx.x] - v; // exclusive
}

__global__ void scan3_kernel(int* __restrict__ rowptr, const int* __restrict__ bsums, int n) {
    int i = blockIdx.x * SCAN_B + threadIdx.x;
    if (i < n) rowptr[i] += bsums[blockIdx.x];
}

// ---- CSR fill (shift trick: rowptr[c] post-fill == segment end) ----
__global__ void fill_kernel(const int* __restrict__ edge, const int* __restrict__ flags,
                            const float* __restrict__ dinv,
                            int* __restrict__ rowptr, int2* __restrict__ csr, int E) {
    int e = blockIdx.x * blockDim.x + threadIdx.x;
    int e64 = flags[1];
    if (e < E) {
        int r = ld_row(edge, e, e64);
        int c = ld_col(edge, e, e64);
        if ((unsigned)r < (unsigned)GN && (unsigned)c < (unsigned)GN) {
            float w = dinv[r] * dinv[c];
            int pos = atomicAdd(&rowptr[c], 1);
            csr[pos] = make_int2(r, __float_as_int(w));
        }
    }
}

// ---- X = bf16(weight); OUT = bf16(alpha[0] * weight) ----
__global__ void init_kernel(const void* __restrict__ w, const void* __restrict__ alpha,
                            const int* __restrict__ flags,
                            __hip_bfloat16* __restrict__ X, __hip_bfloat16* __restrict__ OUT,
                            int n) {
    int i = 4 * (blockIdx.x * blockDim.x + threadIdx.x);
    int wbf = flags[0];
    if (i < n) {
        float a0 = ld_f(alpha, 0, wbf);
        #pragma unroll
        for (int q = 0; q < 4; ++q) {
            float v = ld_f(w, i + q, wbf);
            X[i + q] = __float2bfloat16(v);        // hop-1 operand: exact bf16 input
            OUT[i + q] = __float2bfloat16(a0 * v);
        }
    }
}

// ---- one hop, gather form, fused axpy, 8-way unrolled; bf16 rows ----
// Y[i,:] = bf16( sum_{e: col=i} w_e * X[row_e,:] );  OUT[i,:] += alpha_k * acc
__global__ void gather_kernel(const __hip_bfloat16* __restrict__ X,
                              __hip_bfloat16* __restrict__ Y,
                              __hip_bfloat16* __restrict__ OUT,
                              const int* __restrict__ rowptr, const int2* __restrict__ csr,
                              const void* __restrict__ alpha, const int* __restrict__ flags,
                              int k, int N) {
    int t = blockIdx.x * blockDim.x + threadIdx.x;
    int node = __builtin_amdgcn_readfirstlane(t >> 6);
    int lane = t & 63;
    if (node >= N) return;
    int beg = node ? rowptr[node - 1] : 0;   // post-fill: rowptr[c] = end of segment c
    int end = rowptr[node];
    float a0 = 0.0f, a1 = 0.0f, a2 = 0.0f, a3 = 0.0f;
    float a4 = 0.0f, a5 = 0.0f, a6 = 0.0f, a7 = 0.0f;
    int j = beg;
    for (; j + 8 <= end; j += 8) {
        int2 e0 = csr[j + 0]; int2 e1 = csr[j + 1];
        int2 e2 = csr[j + 2]; int2 e3 = csr[j + 3];
        int2 e4 = csr[j + 4]; int2 e5 = csr[j + 5];
        int2 e6 = csr[j + 6]; int2 e7 = csr[j + 7];
        float x0 = __bfloat162float(X[(size_t)e0.x * GD + lane]);
        float x1 = __bfloat162float(X[(size_t)e1.x * GD + lane]);
        float x2 = __bfloat162float(X[(size_t)e2.x * GD + lane]);
        float x3 = __bfloat162float(X[(size_t)e3.x * GD + lane]);
        float x4 = __bfloat162float(X[(size_t)e4.x * GD + lane]);
        float x5 = __bfloat162float(X[(size_t)e5.x * GD + lane]);
        float x6 = __bfloat162float(X[(size_t)e6.x * GD + lane]);
        float x7 = __bfloat162float(X[(size_t)e7.x * GD + lane]);
        a0 = fmaf(__int_as_float(e0.y), x0, a0);
        a1 = fmaf(__int_as_float(e1.y), x1, a1);
        a2 = fmaf(__int_as_float(e2.y), x2, a2);
        a3 = fmaf(__int_as_float(e3.y), x3, a3);
        a4 = fmaf(__int_as_float(e4.y), x4, a4);
        a5 = fmaf(__int_as_float(e5.y), x5, a5);
        a6 = fmaf(__int_as_float(e6.y), x6, a6);
        a7 = fmaf(__int_as_float(e7.y), x7, a7);
    }
    if (j + 4 <= end) {
        int2 e0 = csr[j + 0]; int2 e1 = csr[j + 1];
        int2 e2 = csr[j + 2]; int2 e3 = csr[j + 3];
        float x0 = __bfloat162float(X[(size_t)e0.x * GD + lane]);
        float x1 = __bfloat162float(X[(size_t)e1.x * GD + lane]);
        float x2 = __bfloat162float(X[(size_t)e2.x * GD + lane]);
        float x3 = __bfloat162float(X[(size_t)e3.x * GD + lane]);
        a0 = fmaf(__int_as_float(e0.y), x0, a0);
        a1 = fmaf(__int_as_float(e1.y), x1, a1);
        a2 = fmaf(__int_as_float(e2.y), x2, a2);
        a3 = fmaf(__int_as_float(e3.y), x3, a3);
        j += 4;
    }
    for (; j < end; ++j) {
        int2 e = csr[j];
        a0 = fmaf(__int_as_float(e.y), __bfloat162float(X[(size_t)e.x * GD + lane]), a0);
    }
    float acc = ((a0 + a1) + (a2 + a3)) + ((a4 + a5) + (a6 + a7));
    size_t o = (size_t)node * GD + lane;
    Y[o] = __float2bfloat16(acc);
    float a = ld_f(alpha, k, flags[0]);
    OUT[o] = __float2bfloat16(__bfloat162float(OUT[o]) + a * acc);
}

// ---- bf16-pair dot helper: 2 elements per uint ----
__device__ __forceinline__ float dot2_bf16(unsigned ua, unsigned ub) {
    float al = __uint_as_float(ua << 16);
    float ah = __uint_as_float(ua & 0xFFFF0000u);
    float bl = __uint_as_float(ub << 16);
    float bh = __uint_as_float(ub & 0xFFFF0000u);
    return fmaf(al, bl, ah * bh);
}

// ---- res[e] = dot(OUT[row[e]], OUT[col[e]]) — 8 threads/edge, 16B loads ----
__global__ void dot_kernel(const __hip_bfloat16* __restrict__ OUT,
                           const int* __restrict__ edge, const int* __restrict__ flags,
                           void* __restrict__ res, int E) {
    int t = blockIdx.x * blockDim.x + threadIdx.x;
    int e = t >> 3;
    int sub = t & 7;
    if (e >= E) return;
    int e64 = flags[1];
    int wbf = flags[0];
    int r = ld_row(edge, e, e64);
    int c = ld_col(edge, e, e64);
    float p = 0.0f;
    if ((unsigned)r < (unsigned)GN && (unsigned)c < (unsigned)GN) {
        uint4 ua = *(const uint4*)(OUT + (size_t)r * GD + sub * 8);
        uint4 ub = *(const uint4*)(OUT + (size_t)c * GD + sub * 8);
        p = (dot2_bf16(ua.x, ub.x) + dot2_bf16(ua.y, ub.y)) +
            (dot2_bf16(ua.z, ub.z) + dot2_bf16(ua.w, ub.w));
    }
    #pragma unroll
    for (int off = 4; off > 0; off >>= 1) p += __shfl_down(p, off, 8);
    if (sub == 0) {
        if (wbf) ((__hip_bfloat16*)res)[e] = __float2bfloat16(p);
        else     ((float*)res)[e] = p;
    }
}

extern "C" void kernel_launch(void* const* d_in, const int* in_sizes, int n_in,
                              void* d_out, int out_size, void* d_ws, size_t ws_size,
                              hipStream_t stream) {
    const int E = GE, N = GN, ND = GN * GD;
    const int nblocks_scan = (N + SCAN_B - 1) / SCAN_B;  // 391

    const void* edge   = d_in[0];
    const void* weight = d_in[1];
    const void* alpha  = d_in[2];

    // Workspace layout (~50 MB total, bf16 feature buffers) — same as round 6
    char* ws = (char*)d_ws;
    int*   flags  = (int*)ws;   ws += 256;
    int*   degi   = (int*)ws;   ws += (((size_t)N * 4 + 255) / 256) * 256;
    float* dinv   = (float*)ws; ws += (((size_t)N * 4 + 255) / 256) * 256;
    int*   rowptr = (int*)ws;   ws += (((size_t)N * 4 + 255) / 256) * 256;
    int*   bsums  = (int*)ws;   ws += 2048;
    int2*  csr    = (int2*)ws;  ws += (size_t)E * 8;              // 9.6 MB
    __hip_bfloat16* X   = (__hip_bfloat16*)ws; ws += (size_t)ND * 2;  // 12.8 MB
    __hip_bfloat16* Y   = (__hip_bfloat16*)ws; ws += (size_t)ND * 2;  // 12.8 MB
    __hip_bfloat16* OUT = (__hip_bfloat16*)ws; ws += (size_t)ND * 2;  // 12.8 MB

    const int B = 256;

    detect_kernel<<<1, 256, 0, stream>>>(weight, edge, flags);

    // CSR build
    hipMemsetAsync(degi, 0, (size_t)N * 4, stream);
    hist_kernel<<<(E + B - 1) / B, B, 0, stream>>>((const int*)edge, flags, degi, E);
    scan1_kernel<<<nblocks_scan, SCAN_B, 0, stream>>>(degi, rowptr, bsums, dinv, N);
    scan2_kernel<<<1, 512, 0, stream>>>(bsums, nblocks_scan);
    scan3_kernel<<<nblocks_scan, SCAN_B, 0, stream>>>(rowptr, bsums, N);
    fill_kernel<<<(E + B - 1) / B, B, 0, stream>>>((const int*)edge, flags, dinv, rowptr, csr, E);

    // X = bf16(weight); OUT = bf16(a0*weight)
    init_kernel<<<(ND / 4 + B - 1) / B, B, 0, stream>>>(weight, alpha, flags, X, OUT, ND);

    // 3 propagation hops (gather + fused axpy, 8-way unrolled, bf16 rows)
    const int ggrid = (int)(((size_t)N * 64 + B - 1) / B);
    gather_kernel<<<ggrid, B, 0, stream>>>(X, Y, OUT, rowptr, csr, alpha, flags, 1, N);
    gather_kernel<<<ggrid, B, 0, stream>>>(Y, X, OUT, rowptr, csr, alpha, flags, 2, N);
    gather_kernel<<<ggrid, B, 0, stream>>>(X, Y, OUT, rowptr, csr, alpha, flags, 3, N);

    // per-edge link scores (8 threads/edge, uint4 row loads)
    dot_kernel<<<(int)(((size_t)E * 8 + B - 1) / B), B, 0, stream>>>(OUT, (const int*)edge, flags, d_out, E);
}